// Round 1
// baseline (1103.519 us; speedup 1.0000x reference)
//
#include <hip/hip_runtime.h>
#include <cstdint>

#define B_  2
#define S_  1024
#define H_  1024
#define NH_ 16
#define DH_ 64
#define F_  4096
#define L_  4
#define M_  (B_*S_)   // 2048 rows in all GEMMs

typedef __bf16 bf16;
typedef __bf16 bf16x8 __attribute__((ext_vector_type(8)));
typedef __bf16 bf16x4 __attribute__((ext_vector_type(4)));
typedef float  f32x4  __attribute__((ext_vector_type(4)));

// ---------------- async global->LDS (16B per lane), CK-style addrspace cast ----
__device__ __forceinline__ void async_ld16(void* lds, const void* g) {
  auto* lp = reinterpret_cast<__attribute__((address_space(3))) unsigned int*>(
      reinterpret_cast<uintptr_t>(lds));
  const auto* gp = reinterpret_cast<const __attribute__((address_space(1))) unsigned int*>(
      reinterpret_cast<uintptr_t>(g));
  __builtin_amdgcn_global_load_lds(gp, lp, 16, 0, 0);
}

__device__ __forceinline__ float gelu_tanh(float x) {
  float u = 0.7978845608028654f * (x + 0.044715f * x * x * x);
  u = fminf(fmaxf(u, -15.f), 15.f);
  float e = __builtin_amdgcn_exp2f(u * 2.8853900817779268f); // exp(2u)
  return 0.5f * x * (1.f + (e - 1.f) / (e + 1.f));
}

// ---------------- weight transpose + fp32->bf16 convert:  W[K][N] -> Wt[N][K] --
__global__ __launch_bounds__(256) void transpose_cvt(
    const float* __restrict__ src, bf16* __restrict__ dst, int K, int N) {
  __shared__ float t[32][33];
  const int n0 = blockIdx.x * 32, k0 = blockIdx.y * 32;
  const size_t so = (size_t)blockIdx.z * K * N;
  const int x = threadIdx.x, y = threadIdx.y;
  #pragma unroll
  for (int i = 0; i < 32; i += 8)
    t[y + i][x] = src[so + (size_t)(k0 + y + i) * N + n0 + x];
  __syncthreads();
  #pragma unroll
  for (int i = 0; i < 32; i += 8)
    dst[so + (size_t)(n0 + y + i) * K + k0 + x] = (bf16)t[x][y + i];
}

// ---------------- x init: copy fp32 x -> xf (running x, = d_out) + bf16 mirror -
__global__ __launch_bounds__(256) void init_x_kernel(
    const float4* __restrict__ x, float4* __restrict__ xf, bf16x4* __restrict__ xb) {
  int i = blockIdx.x * 256 + threadIdx.x;
  float4 v = x[i];
  xf[i] = v;
  bf16x4 b;
  b[0] = (bf16)v.x; b[1] = (bf16)v.y; b[2] = (bf16)v.z; b[3] = (bf16)v.w;
  xb[i] = b;
}

// ---------------- m97-structure GEMM core: C[128x128] = A[M][K] @ Bt[N][K]^T ---
__device__ __forceinline__ void gemm_core(
    const bf16* __restrict__ A, const bf16* __restrict__ Bt, int K,
    int m0, int n0, bf16* As, bf16* Bs, f32x4 (&acc)[4][4]) {
  const int tid = (int)threadIdx.x;
  const int w = tid >> 6, l = tid & 63;
  const int lr = l & 15, lg = l >> 4;
  const int wm = w >> 1, wn = w & 1;
  const int srow = l >> 2;            // 0..15 (staging row within 16-row chunk)
  const int scol = (l & 3) * 8;       // element offset (8 bf16 = 16B)

  const bf16* ag = A  + (size_t)(m0 + w * 32 + srow) * K + scol;
  const bf16* bg = Bt + (size_t)(n0 + w * 32 + srow) * K + scol;
  bf16* asd = As + (w * 32) * 32;
  bf16* bsd = Bs + (w * 32) * 32;

  for (int k0 = 0; k0 < K; k0 += 32) {
    __syncthreads();                  // prior frag reads done before overwrite
    async_ld16(asd,            ag);
    async_ld16(asd + 16 * 32,  ag + (size_t)16 * K);
    async_ld16(bsd,            bg);
    async_ld16(bsd + 16 * 32,  bg + (size_t)16 * K);
    ag += 32; bg += 32;
    __syncthreads();                  // vmcnt(0) drain: LDS tiles ready
    bf16x8 af[4], bv[4];
    #pragma unroll
    for (int i = 0; i < 4; ++i)
      af[i] = *(const bf16x8*)(As + (wm * 64 + i * 16 + lr) * 32 + lg * 8);
    #pragma unroll
    for (int i = 0; i < 4; ++i)
      bv[i] = *(const bf16x8*)(Bs + (wn * 64 + i * 16 + lr) * 32 + lg * 8);
    #pragma unroll
    for (int i = 0; i < 4; ++i)
      #pragma unroll
      for (int j = 0; j < 4; ++j)
        acc[i][j] = __builtin_amdgcn_mfma_f32_16x16x32_bf16(af[i], bv[j], acc[i][j], 0, 0, 0);
  }
}

// MODE 0: out_bf16 = acc+bias | MODE 1: out_bf16 = gelu(acc+bias)
// MODE 2: xf += alpha*(acc+bias) (fp32, in-place) and xb = bf16(xf)
template <int MODE>
__global__ __launch_bounds__(256) void gemm128_kernel(
    const bf16* __restrict__ A, const bf16* __restrict__ Bt,
    const float* __restrict__ bias, bf16* __restrict__ outb,
    float* __restrict__ outf, const float* __restrict__ alphap, int N, int K) {
  __shared__ __align__(16) bf16 As[128 * 32];
  __shared__ __align__(16) bf16 Bs[128 * 32];
  const int m0 = blockIdx.y * 128, n0 = blockIdx.x * 128;
  const f32x4 z4 = {0.f, 0.f, 0.f, 0.f};
  f32x4 acc[4][4];
  #pragma unroll
  for (int i = 0; i < 4; ++i)
    #pragma unroll
    for (int j = 0; j < 4; ++j) acc[i][j] = z4;

  gemm_core(A, Bt, K, m0, n0, As, Bs, acc);

  const int tid = (int)threadIdx.x;
  const int w = tid >> 6, l = tid & 63;
  const int lr = l & 15, lg = l >> 4;
  const int wm = w >> 1, wn = w & 1;
  float alpha = 0.f;
  if (MODE == 2) alpha = *alphap;
  #pragma unroll
  for (int i = 0; i < 4; ++i) {
    const int row0 = m0 + wm * 64 + i * 16 + lg * 4;
    #pragma unroll
    for (int j = 0; j < 4; ++j) {
      const int col = n0 + wn * 64 + j * 16 + lr;
      const float bvx = bias[col];
      #pragma unroll
      for (int r = 0; r < 4; ++r) {
        const size_t idx = (size_t)(row0 + r) * N + col;
        float v = acc[i][j][r] + bvx;
        if (MODE == 1) v = gelu_tanh(v);
        if (MODE == 2) {
          float xn = outf[idx] + alpha * v;
          outf[idx] = xn;
          outb[idx] = (bf16)xn;
        } else {
          outb[idx] = (bf16)v;
        }
      }
    }
  }
}

// QKV fused: grid.z selects {Q,K,V}. Q,K -> [B,S,H] bf16. V -> Vt[B,NH,DH,S].
__global__ __launch_bounds__(256) void gemm_qkv_kernel(
    const bf16* __restrict__ A,
    const bf16* __restrict__ WtQ, const bf16* __restrict__ WtK, const bf16* __restrict__ WtV,
    const float* __restrict__ bq, const float* __restrict__ bk, const float* __restrict__ bvv,
    bf16* __restrict__ qo, bf16* __restrict__ ko, bf16* __restrict__ vt) {
  __shared__ __align__(16) bf16 As[128 * 32];
  __shared__ __align__(16) bf16 Bs[128 * 32];
  const int z = blockIdx.z;
  const bf16* Bt = (z == 0) ? WtQ : (z == 1) ? WtK : WtV;
  const float* bias = (z == 0) ? bq : (z == 1) ? bk : bvv;
  const int m0 = blockIdx.y * 128, n0 = blockIdx.x * 128;
  const f32x4 z4 = {0.f, 0.f, 0.f, 0.f};
  f32x4 acc[4][4];
  #pragma unroll
  for (int i = 0; i < 4; ++i)
    #pragma unroll
    for (int j = 0; j < 4; ++j) acc[i][j] = z4;

  gemm_core(A, Bt, H_, m0, n0, As, Bs, acc);

  const int tid = (int)threadIdx.x;
  const int w = tid >> 6, l = tid & 63;
  const int lr = l & 15, lg = l >> 4;
  const int wm = w >> 1, wn = w & 1;
  if (z < 2) {
    bf16* out = z ? ko : qo;
    #pragma unroll
    for (int i = 0; i < 4; ++i) {
      const int row0 = m0 + wm * 64 + i * 16 + lg * 4;
      #pragma unroll
      for (int j = 0; j < 4; ++j) {
        const int col = n0 + wn * 64 + j * 16 + lr;
        const float bvx = bias[col];
        #pragma unroll
        for (int r = 0; r < 4; ++r)
          out[(size_t)(row0 + r) * H_ + col] = (bf16)(acc[i][j][r] + bvx);
      }
    }
  } else {  // V transposed: Vt[((b*NH+h)*DH+d)*S + s], 4 consecutive s per lane
    #pragma unroll
    for (int i = 0; i < 4; ++i) {
      const int row0 = m0 + wm * 64 + i * 16 + lg * 4;
      const int bb = row0 >> 10, ss = row0 & (S_ - 1);
      #pragma unroll
      for (int j = 0; j < 4; ++j) {
        const int col = n0 + wn * 64 + j * 16 + lr;
        const float bvx = bias[col];
        const int hh = col >> 6, dd = col & 63;
        bf16x4 pk;
        #pragma unroll
        for (int r = 0; r < 4; ++r) pk[r] = (bf16)(acc[i][j][r] + bvx);
        *(bf16x4*)(vt + (((size_t)(bb * NH_ + hh) * DH_ + dd) << 10) + ss) = pk;
      }
    }
  }
}

// ---------------- sync-free flash attention ----------------------------------
// grid (S/64, NH, B), 256 thr = 4 independent waves, 16 q-rows each.
// K frags + V^T frags read straight from global (L2-resident); only P via LDS.
__global__ __launch_bounds__(256) void attn_kernel(
    const bf16* __restrict__ Q, const bf16* __restrict__ Kb,
    const bf16* __restrict__ Vt, const float* __restrict__ mask,
    bf16* __restrict__ Ctx) {
  const int tid = (int)threadIdx.x;
  const int w = tid >> 6, l = tid & 63;
  const int lr = l & 15, lg = l >> 4;
  const int h = blockIdx.y, b = blockIdx.z;
  const int q0 = blockIdx.x * 64 + w * 16;

  __shared__ __align__(16) bf16 Ps[4][16][40];  // per-wave P tile, pad 40 -> no conflicts

  const bf16* qp = Q + ((size_t)(b * S_ + q0 + lr)) * H_ + h * DH_;
  const bf16x8 qa0 = *(const bf16x8*)(qp + lg * 8);
  const bf16x8 qa1 = *(const bf16x8*)(qp + 32 + lg * 8);

  const f32x4 z4 = {0.f, 0.f, 0.f, 0.f};
  f32x4 acc[4];
  #pragma unroll
  for (int dt = 0; dt < 4; ++dt) acc[dt] = z4;
  float mrow[4], ssum[4];
  #pragma unroll
  for (int r = 0; r < 4; ++r) { mrow[r] = -1e30f; ssum[r] = 0.f; }

  const bf16* Kbase = Kb + ((size_t)b * S_) * H_ + h * DH_;
  const bf16* Vbase = Vt + ((size_t)(b * NH_ + h)) * DH_ * S_;
  const float* Mbase = mask + ((size_t)(b * S_ + q0 + lg * 4)) * S_;

  const float c1 = 0.125f * 1.44269504088896f;       // scale * log2(e)
  const float c2 = -10000.f * 1.44269504088896f;     // mask adder * log2(e)

  for (int kv0 = 0; kv0 < S_; kv0 += 32) {
    // --- QK^T: two 16-kv sub-tiles, d reduced 0..63 -------------------------
    f32x4 st[2];
    #pragma unroll
    for (int t = 0; t < 2; ++t) {
      const bf16* kp = Kbase + (size_t)(kv0 + t * 16 + lr) * H_;
      bf16x8 k0v = *(const bf16x8*)(kp + lg * 8);
      bf16x8 k1v = *(const bf16x8*)(kp + 32 + lg * 8);
      f32x4 s = __builtin_amdgcn_mfma_f32_16x16x32_bf16(qa0, k0v, z4, 0, 0, 0);
      st[t] = __builtin_amdgcn_mfma_f32_16x16x32_bf16(qa1, k1v, s, 0, 0, 0);
    }
    // --- scale + mask (base-2 domain) --------------------------------------
    float sv[2][4];
    #pragma unroll
    for (int t = 0; t < 2; ++t)
      #pragma unroll
      for (int r = 0; r < 4; ++r) {
        float mv = Mbase[(size_t)r * S_ + kv0 + t * 16 + lr];
        sv[t][r] = st[t][r] * c1 + (1.f - mv) * c2;
      }
    // --- online softmax: row max over 32 kv (lanes lr within 16-group) -----
    float fsc[4];
    #pragma unroll
    for (int r = 0; r < 4; ++r) {
      float nm = fmaxf(sv[0][r], sv[1][r]);
      nm = fmaxf(nm, __shfl_xor(nm, 1));
      nm = fmaxf(nm, __shfl_xor(nm, 2));
      nm = fmaxf(nm, __shfl_xor(nm, 4));
      nm = fmaxf(nm, __shfl_xor(nm, 8));
      float newm = fmaxf(mrow[r], nm);
      fsc[r] = __builtin_amdgcn_exp2f(mrow[r] - newm);
      mrow[r] = newm;
    }
    bf16 pb[2][4];
    float pr[2][4];
    #pragma unroll
    for (int t = 0; t < 2; ++t)
      #pragma unroll
      for (int r = 0; r < 4; ++r) {
        float p = __builtin_amdgcn_exp2f(sv[t][r] - mrow[r]);
        pb[t][r] = (bf16)p;
        pr[t][r] = (float)pb[t][r];   // sum the rounded value (matches PV)
      }
    #pragma unroll
    for (int r = 0; r < 4; ++r) {
      float rs = pr[0][r] + pr[1][r];
      rs += __shfl_xor(rs, 1); rs += __shfl_xor(rs, 2);
      rs += __shfl_xor(rs, 4); rs += __shfl_xor(rs, 8);
      ssum[r] = ssum[r] * fsc[r] + rs;
    }
    #pragma unroll
    for (int dt = 0; dt < 4; ++dt)
      #pragma unroll
      for (int r = 0; r < 4; ++r) acc[dt][r] *= fsc[r];
    // --- P -> LDS (per-wave private; same-wave lgkm deps handled by compiler)
    #pragma unroll
    for (int t = 0; t < 2; ++t)
      #pragma unroll
      for (int r = 0; r < 4; ++r) Ps[w][lg * 4 + r][t * 16 + lr] = pb[t][r];
    const bf16x8 pa = *(const bf16x8*)&Ps[w][lr][lg * 8];
    // --- PV: B-frag straight from V^T in global (d-row, kv-contiguous) -----
    #pragma unroll
    for (int dt = 0; dt < 4; ++dt) {
      bf16x8 vb = *(const bf16x8*)(Vbase + (size_t)(dt * 16 + lr) * S_ + kv0 + lg * 8);
      acc[dt] = __builtin_amdgcn_mfma_f32_16x16x32_bf16(pa, vb, acc[dt], 0, 0, 0);
    }
  }
  float inv[4];
  #pragma unroll
  for (int r = 0; r < 4; ++r) inv[r] = 1.f / ssum[r];
  bf16* cp = Ctx + ((size_t)(b * S_ + q0 + lg * 4)) * H_ + h * DH_;
  #pragma unroll
  for (int dt = 0; dt < 4; ++dt)
    #pragma unroll
    for (int r = 0; r < 4; ++r)
      cp[(size_t)r * H_ + dt * 16 + lr] = (bf16)(acc[dt][r] * inv[r]);
}

// ---------------- launcher ----------------------------------------------------
extern "C" void kernel_launch(void* const* d_in, const int* in_sizes, int n_in,
                              void* d_out, int out_size, void* d_ws, size_t ws_size,
                              hipStream_t stream) {
  (void)in_sizes; (void)n_in; (void)out_size; (void)ws_size;
  const float* x    = (const float*)d_in[0];
  const float* mask = (const float*)d_in[1];
  const float* wq   = (const float*)d_in[2];
  const float* bq   = (const float*)d_in[3];
  const float* wk   = (const float*)d_in[4];
  const float* bk   = (const float*)d_in[5];
  const float* wv   = (const float*)d_in[6];
  const float* bv   = (const float*)d_in[7];
  const float* wo   = (const float*)d_in[8];
  const float* bo   = (const float*)d_in[9];
  const float* aat  = (const float*)d_in[10];
  const float* wi   = (const float*)d_in[11];
  const float* bi   = (const float*)d_in[12];
  const float* wf   = (const float*)d_in[13];
  const float* bf_  = (const float*)d_in[14];
  const float* afn  = (const float*)d_in[15];

  char* ws = (char*)d_ws;
  size_t o = 0;
  bf16* WtQ = (bf16*)(ws + o); o += (size_t)L_ * H_ * H_ * 2;  //  8MB
  bf16* WtK = (bf16*)(ws + o); o += (size_t)L_ * H_ * H_ * 2;  //  8MB
  bf16* WtV = (bf16*)(ws + o); o += (size_t)L_ * H_ * H_ * 2;  //  8MB
  bf16* WtO = (bf16*)(ws + o); o += (size_t)L_ * H_ * H_ * 2;  //  8MB
  bf16* WtI = (bf16*)(ws + o); o += (size_t)L_ * H_ * F_ * 2;  // 32MB
  bf16* WtF = (bf16*)(ws + o); o += (size_t)L_ * F_ * H_ * 2;  // 32MB
  bf16* xb  = (bf16*)(ws + o); o += (size_t)M_ * H_ * 2;       //  4MB
  bf16* qb  = (bf16*)(ws + o); o += (size_t)M_ * H_ * 2;
  bf16* kbf = (bf16*)(ws + o); o += (size_t)M_ * H_ * 2;
  bf16* vt  = (bf16*)(ws + o); o += (size_t)M_ * H_ * 2;
  bf16* ctx = (bf16*)(ws + o); o += (size_t)M_ * H_ * 2;
  bf16* itm = (bf16*)(ws + o); o += (size_t)M_ * F_ * 2;       // 16MB  (total 132MB)

  float* xf = (float*)d_out;  // running x lives in d_out (fp32)

  const dim3 tb(32, 8);
  transpose_cvt<<<dim3(H_/32, H_/32, L_), tb, 0, stream>>>(wq, WtQ, H_, H_);
  transpose_cvt<<<dim3(H_/32, H_/32, L_), tb, 0, stream>>>(wk, WtK, H_, H_);
  transpose_cvt<<<dim3(H_/32, H_/32, L_), tb, 0, stream>>>(wv, WtV, H_, H_);
  transpose_cvt<<<dim3(H_/32, H_/32, L_), tb, 0, stream>>>(wo, WtO, H_, H_);
  transpose_cvt<<<dim3(F_/32, H_/32, L_), tb, 0, stream>>>(wi, WtI, H_, F_);
  transpose_cvt<<<dim3(H_/32, F_/32, L_), tb, 0, stream>>>(wf, WtF, F_, H_);
  init_x_kernel<<<dim3((M_ * H_ / 4) / 256), 256, 0, stream>>>(
      (const float4*)x, (float4*)xf, (bf16x4*)xb);

  for (int l = 0; l < L_; ++l) {
    gemm_qkv_kernel<<<dim3(H_/128, M_/128, 3), 256, 0, stream>>>(
        xb, WtQ + (size_t)l * H_ * H_, WtK + (size_t)l * H_ * H_, WtV + (size_t)l * H_ * H_,
        bq + l * H_, bk + l * H_, bv + l * H_, qb, kbf, vt);
    attn_kernel<<<dim3(S_/64, NH_, B_), 256, 0, stream>>>(qb, kbf, vt, mask, ctx);
    gemm128_kernel<2><<<dim3(H_/128, M_/128), 256, 0, stream>>>(
        ctx, WtO + (size_t)l * H_ * H_, bo + l * H_, xb, xf, aat + l, H_, H_);
    gemm128_kernel<1><<<dim3(F_/128, M_/128), 256, 0, stream>>>(
        xb, WtI + (size_t)l * H_ * F_, bi + l * F_, itm, nullptr, nullptr, F_, H_);
    gemm128_kernel<2><<<dim3(H_/128, M_/128), 256, 0, stream>>>(
        itm, WtF + (size_t)l * F_ * H_, bf_ + l * H_, xb, xf, afn + l, H_, F_);
  }
}

// Round 2
// 857.771 us; speedup vs baseline: 1.2865x; 1.2865x over previous
//
#include <hip/hip_runtime.h>
#include <cstdint>

#define B_  2
#define S_  1024
#define H_  1024
#define NH_ 16
#define DH_ 64
#define F_  4096
#define L_  4
#define M_  (B_*S_)   // 2048 rows in all GEMMs

typedef __bf16 bf16;
typedef __bf16 bf16x8 __attribute__((ext_vector_type(8)));
typedef __bf16 bf16x4 __attribute__((ext_vector_type(4)));
typedef float  f32x4  __attribute__((ext_vector_type(4)));

// ---------------- async global->LDS (16B per lane), CK-style addrspace cast ----
__device__ __forceinline__ void async_ld16(void* lds, const void* g) {
  auto* lp = reinterpret_cast<__attribute__((address_space(3))) unsigned int*>(
      reinterpret_cast<uintptr_t>(lds));
  const auto* gp = reinterpret_cast<const __attribute__((address_space(1))) unsigned int*>(
      reinterpret_cast<uintptr_t>(g));
  __builtin_amdgcn_global_load_lds(gp, lp, 16, 0, 0);
}

__device__ __forceinline__ float gelu_tanh(float x) {
  float u = 0.7978845608028654f * (x + 0.044715f * x * x * x);
  u = fminf(fmaxf(u, -15.f), 15.f);
  float e = __builtin_amdgcn_exp2f(u * 2.8853900817779268f); // exp(2u)
  return 0.5f * x * (1.f + (e - 1.f) / (e + 1.f));
}

// ---------------- weight transpose + fp32->bf16 convert:  W[K][N] -> Wt[N][K] --
__global__ __launch_bounds__(256) void transpose_cvt(
    const float* __restrict__ src, bf16* __restrict__ dst, int K, int N) {
  __shared__ float t[32][33];
  const int n0 = blockIdx.x * 32, k0 = blockIdx.y * 32;
  const size_t so = (size_t)blockIdx.z * K * N;
  const int x = threadIdx.x, y = threadIdx.y;
  #pragma unroll
  for (int i = 0; i < 32; i += 8)
    t[y + i][x] = src[so + (size_t)(k0 + y + i) * N + n0 + x];
  __syncthreads();
  #pragma unroll
  for (int i = 0; i < 32; i += 8)
    dst[so + (size_t)(n0 + y + i) * K + k0 + x] = (bf16)t[x][y + i];
}

// ---------------- x init: copy fp32 x -> xf (running x, = d_out) + bf16 mirror -
__global__ __launch_bounds__(256) void init_x_kernel(
    const float4* __restrict__ x, float4* __restrict__ xf, bf16x4* __restrict__ xb) {
  int i = blockIdx.x * 256 + threadIdx.x;
  float4 v = x[i];
  xf[i] = v;
  bf16x4 b;
  b[0] = (bf16)v.x; b[1] = (bf16)v.y; b[2] = (bf16)v.z; b[3] = (bf16)v.w;
  xb[i] = b;
}

// ---------------- m97-structure GEMM core: C[128x128] = A[.][ld] @ Bt[.][ld]^T -
// ld = row stride of both A and Bt; kLen = K-extent to accumulate (<= ld).
__device__ __forceinline__ void gemm_core(
    const bf16* __restrict__ A, const bf16* __restrict__ Bt, int ld, int kLen,
    int m0, int n0, bf16* As, bf16* Bs, f32x4 (&acc)[4][4]) {
  const int tid = (int)threadIdx.x;
  const int w = tid >> 6, l = tid & 63;
  const int lr = l & 15, lg = l >> 4;
  const int wm = w >> 1, wn = w & 1;
  const int srow = l >> 2;            // 0..15 (staging row within 16-row chunk)
  const int scol = (l & 3) * 8;       // element offset (8 bf16 = 16B)

  const bf16* ag = A  + (size_t)(m0 + w * 32 + srow) * ld + scol;
  const bf16* bg = Bt + (size_t)(n0 + w * 32 + srow) * ld + scol;
  bf16* asd = As + (w * 32) * 32;
  bf16* bsd = Bs + (w * 32) * 32;

  for (int k0 = 0; k0 < kLen; k0 += 32) {
    __syncthreads();                  // prior frag reads done before overwrite
    async_ld16(asd,            ag);
    async_ld16(asd + 16 * 32,  ag + (size_t)16 * ld);
    async_ld16(bsd,            bg);
    async_ld16(bsd + 16 * 32,  bg + (size_t)16 * ld);
    ag += 32; bg += 32;
    __syncthreads();                  // vmcnt(0) drain: LDS tiles ready
    bf16x8 af[4], bv[4];
    #pragma unroll
    for (int i = 0; i < 4; ++i)
      af[i] = *(const bf16x8*)(As + (wm * 64 + i * 16 + lr) * 32 + lg * 8);
    #pragma unroll
    for (int i = 0; i < 4; ++i)
      bv[i] = *(const bf16x8*)(Bs + (wn * 64 + i * 16 + lr) * 32 + lg * 8);
    #pragma unroll
    for (int i = 0; i < 4; ++i)
      #pragma unroll
      for (int j = 0; j < 4; ++j)
        acc[i][j] = __builtin_amdgcn_mfma_f32_16x16x32_bf16(af[i], bv[j], acc[i][j], 0, 0, 0);
  }
}

// MODE 0: out_bf16 = acc+bias | MODE 1: out_bf16 = gelu(acc+bias)
// MODE 2: xf += alpha*(acc+bias) (fp32, in-place) and xb = bf16(xf)
// MODE 3: fp32 partial (no bias) -> part[z*M*N + row*N + col], split-K over grid.z
template <int MODE>
__global__ __launch_bounds__(256) void gemm128_kernel(
    const bf16* __restrict__ A, const bf16* __restrict__ Bt,
    const float* __restrict__ bias, bf16* __restrict__ outb,
    float* __restrict__ outf, const float* __restrict__ alphap,
    float* __restrict__ part, int N, int K, int kSlice) {
  __shared__ __align__(16) bf16 As[128 * 32];
  __shared__ __align__(16) bf16 Bs[128 * 32];
  const int m0 = blockIdx.y * 128, n0 = blockIdx.x * 128;
  const int z = blockIdx.z;
  const f32x4 z4 = {0.f, 0.f, 0.f, 0.f};
  f32x4 acc[4][4];
  #pragma unroll
  for (int i = 0; i < 4; ++i)
    #pragma unroll
    for (int j = 0; j < 4; ++j) acc[i][j] = z4;

  gemm_core(A + (size_t)z * kSlice, Bt + (size_t)z * kSlice, K, kSlice,
            m0, n0, As, Bs, acc);

  const int tid = (int)threadIdx.x;
  const int w = tid >> 6, l = tid & 63;
  const int lr = l & 15, lg = l >> 4;
  const int wm = w >> 1, wn = w & 1;
  float alpha = 0.f;
  if (MODE == 2) alpha = *alphap;
  const size_t pbase = (MODE == 3) ? (size_t)z * M_ * (size_t)N : 0;
  #pragma unroll
  for (int i = 0; i < 4; ++i) {
    const int row0 = m0 + wm * 64 + i * 16 + lg * 4;
    #pragma unroll
    for (int j = 0; j < 4; ++j) {
      const int col = n0 + wn * 64 + j * 16 + lr;
      const float bvx = (MODE == 3) ? 0.f : bias[col];
      #pragma unroll
      for (int r = 0; r < 4; ++r) {
        const size_t idx = (size_t)(row0 + r) * N + col;
        float v = acc[i][j][r] + bvx;
        if (MODE == 3) {
          part[pbase + idx] = v;
        } else if (MODE == 1) {
          outb[idx] = (bf16)gelu_tanh(v);
        } else if (MODE == 2) {
          float xn = outf[idx] + alpha * v;
          outf[idx] = xn;
          outb[idx] = (bf16)xn;
        } else {
          outb[idx] = (bf16)v;
        }
      }
    }
  }
}

// ---------------- split-K reduce + bias + ReZero residual ---------------------
// xf += alpha * (sum_z part[z] + bias); xb = bf16(xf). Vectorized float4.
__global__ __launch_bounds__(256) void reduce_residual(
    const float4* __restrict__ part, const float* __restrict__ bias,
    const float* __restrict__ alphap, float4* __restrict__ xf,
    bf16x4* __restrict__ xb) {
  const int i = blockIdx.x * 256 + (int)threadIdx.x;   // over M_*H_/4
  const int nper = M_ * H_ / 4;
  float4 s = part[i];
  #pragma unroll
  for (int zz = 1; zz < 4; ++zz) {
    float4 p = part[i + (size_t)zz * nper];
    s.x += p.x; s.y += p.y; s.z += p.z; s.w += p.w;
  }
  const int col = (i * 4) & (H_ - 1);
  const float4 b4 = *(const float4*)(bias + col);
  const float a = *alphap;
  float4 xv = xf[i];
  xv.x += a * (s.x + b4.x);
  xv.y += a * (s.y + b4.y);
  xv.z += a * (s.z + b4.z);
  xv.w += a * (s.w + b4.w);
  xf[i] = xv;
  bf16x4 bb;
  bb[0] = (bf16)xv.x; bb[1] = (bf16)xv.y; bb[2] = (bf16)xv.z; bb[3] = (bf16)xv.w;
  xb[i] = bb;
}

// QKV fused: grid.z selects {Q,K,V}. Q,K -> [B,S,H] bf16. V -> Vt[B,NH,DH,S].
__global__ __launch_bounds__(256) void gemm_qkv_kernel(
    const bf16* __restrict__ A,
    const bf16* __restrict__ WtQ, const bf16* __restrict__ WtK, const bf16* __restrict__ WtV,
    const float* __restrict__ bq, const float* __restrict__ bk, const float* __restrict__ bvv,
    bf16* __restrict__ qo, bf16* __restrict__ ko, bf16* __restrict__ vt) {
  __shared__ __align__(16) bf16 As[128 * 32];
  __shared__ __align__(16) bf16 Bs[128 * 32];
  const int z = blockIdx.z;
  const bf16* Bt = (z == 0) ? WtQ : (z == 1) ? WtK : WtV;
  const float* bias = (z == 0) ? bq : (z == 1) ? bk : bvv;
  const int m0 = blockIdx.y * 128, n0 = blockIdx.x * 128;
  const f32x4 z4 = {0.f, 0.f, 0.f, 0.f};
  f32x4 acc[4][4];
  #pragma unroll
  for (int i = 0; i < 4; ++i)
    #pragma unroll
    for (int j = 0; j < 4; ++j) acc[i][j] = z4;

  gemm_core(A, Bt, H_, H_, m0, n0, As, Bs, acc);

  const int tid = (int)threadIdx.x;
  const int w = tid >> 6, l = tid & 63;
  const int lr = l & 15, lg = l >> 4;
  const int wm = w >> 1, wn = w & 1;
  if (z < 2) {
    bf16* out = z ? ko : qo;
    #pragma unroll
    for (int i = 0; i < 4; ++i) {
      const int row0 = m0 + wm * 64 + i * 16 + lg * 4;
      #pragma unroll
      for (int j = 0; j < 4; ++j) {
        const int col = n0 + wn * 64 + j * 16 + lr;
        const float bvx = bias[col];
        #pragma unroll
        for (int r = 0; r < 4; ++r)
          out[(size_t)(row0 + r) * H_ + col] = (bf16)(acc[i][j][r] + bvx);
      }
    }
  } else {  // V transposed: Vt[((b*NH+h)*DH+d)*S + s], 4 consecutive s per lane
    #pragma unroll
    for (int i = 0; i < 4; ++i) {
      const int row0 = m0 + wm * 64 + i * 16 + lg * 4;
      const int bb = row0 >> 10, ss = row0 & (S_ - 1);
      #pragma unroll
      for (int j = 0; j < 4; ++j) {
        const int col = n0 + wn * 64 + j * 16 + lr;
        const float bvx = bias[col];
        const int hh = col >> 6, dd = col & 63;
        bf16x4 pk;
        #pragma unroll
        for (int r = 0; r < 4; ++r) pk[r] = (bf16)(acc[i][j][r] + bvx);
        *(bf16x4*)(vt + (((size_t)(bb * NH_ + hh) * DH_ + dd) << 10) + ss) = pk;
      }
    }
  }
}

// ---------------- sync-free flash attention ----------------------------------
// grid (S/64, NH, B), 256 thr = 4 independent waves, 16 q-rows each.
// K frags + V^T frags read straight from global (L2-resident); only P via LDS.
__global__ __launch_bounds__(256) void attn_kernel(
    const bf16* __restrict__ Q, const bf16* __restrict__ Kb,
    const bf16* __restrict__ Vt, const float* __restrict__ mask,
    bf16* __restrict__ Ctx) {
  const int tid = (int)threadIdx.x;
  const int w = tid >> 6, l = tid & 63;
  const int lr = l & 15, lg = l >> 4;
  const int h = blockIdx.y, b = blockIdx.z;
  const int q0 = blockIdx.x * 64 + w * 16;

  __shared__ __align__(16) bf16 Ps[4][16][40];  // per-wave P tile, pad 40 -> no conflicts

  const bf16* qp = Q + ((size_t)(b * S_ + q0 + lr)) * H_ + h * DH_;
  const bf16x8 qa0 = *(const bf16x8*)(qp + lg * 8);
  const bf16x8 qa1 = *(const bf16x8*)(qp + 32 + lg * 8);

  const f32x4 z4 = {0.f, 0.f, 0.f, 0.f};
  f32x4 acc[4];
  #pragma unroll
  for (int dt = 0; dt < 4; ++dt) acc[dt] = z4;
  float mrow[4], ssum[4];
  #pragma unroll
  for (int r = 0; r < 4; ++r) { mrow[r] = -1e30f; ssum[r] = 0.f; }

  const bf16* Kbase = Kb + ((size_t)b * S_) * H_ + h * DH_;
  const bf16* Vbase = Vt + ((size_t)(b * NH_ + h)) * DH_ * S_;
  const float* Mbase = mask + ((size_t)(b * S_ + q0 + lg * 4)) * S_;

  const float c1 = 0.125f * 1.44269504088896f;       // scale * log2(e)
  const float c2 = -10000.f * 1.44269504088896f;     // mask adder * log2(e)

  for (int kv0 = 0; kv0 < S_; kv0 += 32) {
    // --- QK^T: two 16-kv sub-tiles, d reduced 0..63 -------------------------
    f32x4 st[2];
    #pragma unroll
    for (int t = 0; t < 2; ++t) {
      const bf16* kp = Kbase + (size_t)(kv0 + t * 16 + lr) * H_;
      bf16x8 k0v = *(const bf16x8*)(kp + lg * 8);
      bf16x8 k1v = *(const bf16x8*)(kp + 32 + lg * 8);
      f32x4 s = __builtin_amdgcn_mfma_f32_16x16x32_bf16(qa0, k0v, z4, 0, 0, 0);
      st[t] = __builtin_amdgcn_mfma_f32_16x16x32_bf16(qa1, k1v, s, 0, 0, 0);
    }
    // --- scale + mask (base-2 domain) --------------------------------------
    float sv[2][4];
    #pragma unroll
    for (int t = 0; t < 2; ++t)
      #pragma unroll
      for (int r = 0; r < 4; ++r) {
        float mv = Mbase[(size_t)r * S_ + kv0 + t * 16 + lr];
        sv[t][r] = st[t][r] * c1 + (1.f - mv) * c2;
      }
    // --- online softmax: row max over 32 kv (lanes lr within 16-group) -----
    float fsc[4];
    #pragma unroll
    for (int r = 0; r < 4; ++r) {
      float nm = fmaxf(sv[0][r], sv[1][r]);
      nm = fmaxf(nm, __shfl_xor(nm, 1));
      nm = fmaxf(nm, __shfl_xor(nm, 2));
      nm = fmaxf(nm, __shfl_xor(nm, 4));
      nm = fmaxf(nm, __shfl_xor(nm, 8));
      float newm = fmaxf(mrow[r], nm);
      fsc[r] = __builtin_amdgcn_exp2f(mrow[r] - newm);
      mrow[r] = newm;
    }
    bf16 pb[2][4];
    float pr[2][4];
    #pragma unroll
    for (int t = 0; t < 2; ++t)
      #pragma unroll
      for (int r = 0; r < 4; ++r) {
        float p = __builtin_amdgcn_exp2f(sv[t][r] - mrow[r]);
        pb[t][r] = (bf16)p;
        pr[t][r] = (float)pb[t][r];   // sum the rounded value (matches PV)
      }
    #pragma unroll
    for (int r = 0; r < 4; ++r) {
      float rs = pr[0][r] + pr[1][r];
      rs += __shfl_xor(rs, 1); rs += __shfl_xor(rs, 2);
      rs += __shfl_xor(rs, 4); rs += __shfl_xor(rs, 8);
      ssum[r] = ssum[r] * fsc[r] + rs;
    }
    #pragma unroll
    for (int dt = 0; dt < 4; ++dt)
      #pragma unroll
      for (int r = 0; r < 4; ++r) acc[dt][r] *= fsc[r];
    // --- P -> LDS (per-wave private; same-wave lgkm deps handled by compiler)
    #pragma unroll
    for (int t = 0; t < 2; ++t)
      #pragma unroll
      for (int r = 0; r < 4; ++r) Ps[w][lg * 4 + r][t * 16 + lr] = pb[t][r];
    const bf16x8 pa = *(const bf16x8*)&Ps[w][lr][lg * 8];
    // --- PV: B-frag straight from V^T in global (d-row, kv-contiguous) -----
    #pragma unroll
    for (int dt = 0; dt < 4; ++dt) {
      bf16x8 vb = *(const bf16x8*)(Vbase + (size_t)(dt * 16 + lr) * S_ + kv0 + lg * 8);
      acc[dt] = __builtin_amdgcn_mfma_f32_16x16x32_bf16(pa, vb, acc[dt], 0, 0, 0);
    }
  }
  float inv[4];
  #pragma unroll
  for (int r = 0; r < 4; ++r) inv[r] = 1.f / ssum[r];
  bf16* cp = Ctx + ((size_t)(b * S_ + q0 + lg * 4)) * H_ + h * DH_;
  #pragma unroll
  for (int dt = 0; dt < 4; ++dt)
    #pragma unroll
    for (int r = 0; r < 4; ++r)
      cp[(size_t)r * H_ + dt * 16 + lr] = (bf16)(acc[dt][r] * inv[r]);
}

// ---------------- launcher ----------------------------------------------------
extern "C" void kernel_launch(void* const* d_in, const int* in_sizes, int n_in,
                              void* d_out, int out_size, void* d_ws, size_t ws_size,
                              hipStream_t stream) {
  (void)in_sizes; (void)n_in; (void)out_size;
  const float* x    = (const float*)d_in[0];
  const float* mask = (const float*)d_in[1];
  const float* wq   = (const float*)d_in[2];
  const float* bq   = (const float*)d_in[3];
  const float* wk   = (const float*)d_in[4];
  const float* bk   = (const float*)d_in[5];
  const float* wv   = (const float*)d_in[6];
  const float* bv   = (const float*)d_in[7];
  const float* wo   = (const float*)d_in[8];
  const float* bo   = (const float*)d_in[9];
  const float* aat  = (const float*)d_in[10];
  const float* wi   = (const float*)d_in[11];
  const float* bi   = (const float*)d_in[12];
  const float* wf   = (const float*)d_in[13];
  const float* bf_  = (const float*)d_in[14];
  const float* afn  = (const float*)d_in[15];

  char* ws = (char*)d_ws;
  size_t o = 0;
  bf16* WtQ = (bf16*)(ws + o); o += (size_t)L_ * H_ * H_ * 2;  //  8MB
  bf16* WtK = (bf16*)(ws + o); o += (size_t)L_ * H_ * H_ * 2;  //  8MB
  bf16* WtV = (bf16*)(ws + o); o += (size_t)L_ * H_ * H_ * 2;  //  8MB
  bf16* WtO = (bf16*)(ws + o); o += (size_t)L_ * H_ * H_ * 2;  //  8MB
  bf16* WtI = (bf16*)(ws + o); o += (size_t)L_ * H_ * F_ * 2;  // 32MB
  bf16* WtF = (bf16*)(ws + o); o += (size_t)L_ * F_ * H_ * 2;  // 32MB
  bf16* xb  = (bf16*)(ws + o); o += (size_t)M_ * H_ * 2;       //  4MB
  bf16* qb  = (bf16*)(ws + o); o += (size_t)M_ * H_ * 2;
  bf16* kbf = (bf16*)(ws + o); o += (size_t)M_ * H_ * 2;
  bf16* vt  = (bf16*)(ws + o); o += (size_t)M_ * H_ * 2;
  bf16* ctx = (bf16*)(ws + o); o += (size_t)M_ * H_ * 2;
  bf16* itm = (bf16*)(ws + o); o += (size_t)M_ * F_ * 2;       // 16MB  (132MB)
  float* part = (float*)(ws + o); o += (size_t)4 * M_ * H_ * 4; // 32MB  (164MB)
  const bool use_split = (ws_size >= o);

  float* xf = (float*)d_out;  // running x lives in d_out (fp32)

  const dim3 tb(32, 8);
  transpose_cvt<<<dim3(H_/32, H_/32, L_), tb, 0, stream>>>(wq, WtQ, H_, H_);
  transpose_cvt<<<dim3(H_/32, H_/32, L_), tb, 0, stream>>>(wk, WtK, H_, H_);
  transpose_cvt<<<dim3(H_/32, H_/32, L_), tb, 0, stream>>>(wv, WtV, H_, H_);
  transpose_cvt<<<dim3(H_/32, H_/32, L_), tb, 0, stream>>>(wo, WtO, H_, H_);
  transpose_cvt<<<dim3(F_/32, H_/32, L_), tb, 0, stream>>>(wi, WtI, H_, F_);
  transpose_cvt<<<dim3(H_/32, F_/32, L_), tb, 0, stream>>>(wf, WtF, F_, H_);
  init_x_kernel<<<dim3((M_ * H_ / 4) / 256), 256, 0, stream>>>(
      (const float4*)x, (float4*)xf, (bf16x4*)xb);

  for (int l = 0; l < L_; ++l) {
    gemm_qkv_kernel<<<dim3(H_/128, M_/128, 3), 256, 0, stream>>>(
        xb, WtQ + (size_t)l * H_ * H_, WtK + (size_t)l * H_ * H_, WtV + (size_t)l * H_ * H_,
        bq + l * H_, bk + l * H_, bv + l * H_, qb, kbf, vt);
    attn_kernel<<<dim3(S_/64, NH_, B_), 256, 0, stream>>>(qb, kbf, vt, mask, ctx);
    if (use_split) {
      // O-proj: split-K=4 (K=1024 -> 256/slice), 512 blocks
      gemm128_kernel<3><<<dim3(H_/128, M_/128, 4), 256, 0, stream>>>(
          ctx, WtO + (size_t)l * H_ * H_, nullptr, nullptr, nullptr, nullptr,
          part, H_, H_, H_ / 4);
      reduce_residual<<<dim3((M_ * H_ / 4) / 256), 256, 0, stream>>>(
          (const float4*)part, bo + l * H_, aat + l, (float4*)xf, (bf16x4*)xb);
    } else {
      gemm128_kernel<2><<<dim3(H_/128, M_/128), 256, 0, stream>>>(
          ctx, WtO + (size_t)l * H_ * H_, bo + l * H_, xb, xf, aat + l,
          nullptr, H_, H_, H_);
    }
    gemm128_kernel<1><<<dim3(F_/128, M_/128), 256, 0, stream>>>(
        xb, WtI + (size_t)l * H_ * F_, bi + l * F_, itm, nullptr, nullptr,
        nullptr, F_, H_, H_);
    if (use_split) {
      // FFN2: split-K=4 (K=4096 -> 1024/slice), 512 blocks
      gemm128_kernel<3><<<dim3(H_/128, M_/128, 4), 256, 0, stream>>>(
          itm, WtF + (size_t)l * F_ * H_, nullptr, nullptr, nullptr, nullptr,
          part, H_, F_, F_ / 4);
      reduce_residual<<<dim3((M_ * H_ / 4) / 256), 256, 0, stream>>>(
          (const float4*)part, bf_ + l * H_, afn + l, (float4*)xf, (bf16x4*)xb);
    } else {
      gemm128_kernel<2><<<dim3(H_/128, M_/128), 256, 0, stream>>>(
          itm, WtF + (size_t)l * F_ * H_, bf_ + l * H_, xb, xf, afn + l,
          nullptr, H_, F_, F_);
    }
  }
}